// Round 1
// baseline (433.854 us; speedup 1.0000x reference)
//
#include <hip/hip_runtime.h>

// SelfAttention: x[4096,1024] f32; Wq,Wk,Wv[1024,1024] f32 (uniform[0,1)).
// out = softmax((xWq)(xWk)^T / 32) @ (xWv), f32 [4096,1024].
//
// Numerics: scores are huge (near-one-hot softmax) -> need fp32-quality
// scores. Use fp16 hi/lo split MFMA (3 mfma per product) for x@W and QK^T.
// ws layout (needs 104 MiB):
//   Qh:0  Ql:8M  Kh:16M  Kl:24M  V:32M  S(f32):40M..104M  P(f16): reuses 0..32M

typedef _Float16 f16;
typedef f16 f16x8 __attribute__((ext_vector_type(8)));
typedef f16 f16x4v __attribute__((ext_vector_type(4)));
typedef float f32x4 __attribute__((ext_vector_type(4)));
typedef unsigned short u16;
typedef u16 u16x8 __attribute__((ext_vector_type(8)));

#define LDP 40  // padded LDS k-stride (elements); 80B row stride keeps b128 aligned

__device__ __forceinline__ void split_f32(float v, u16& hb, u16& lb) {
  f16 hh = (f16)v;
  f16 ll = (f16)(v - (float)hh);
  hb = __builtin_bit_cast(u16, hh);
  lb = __builtin_bit_cast(u16, ll);
}

// ---------------- K1: Q/K/V = x @ W  (split fp16, 3-MFMA) ----------------
__global__ __launch_bounds__(256) void k_qkv(
    const float* __restrict__ x, const float* __restrict__ Wq,
    const float* __restrict__ Wk, const float* __restrict__ Wv,
    f16* __restrict__ Qh, f16* __restrict__ Ql,
    f16* __restrict__ Kh, f16* __restrict__ Kl, f16* __restrict__ Vh) {
  __shared__ u16 sAh[128][LDP], sAl[128][LDP], sBh[128][LDP], sBl[128][LDP];
  const int z = blockIdx.z;
  const float* __restrict__ W = (z == 0) ? Wq : (z == 1) ? Wk : Wv;
  const int tid = threadIdx.x;
  const int lane = tid & 63, wid = tid >> 6;
  const int wr = wid >> 1, wc = wid & 1;
  const int brow = blockIdx.x * 128, bcol = blockIdx.y * 128;
  const int ar = lane & 15, k0 = (lane >> 4) * 8;
  const int ra = tid >> 1, ca = (tid & 1) * 16;  // A staging: 2 thr/row, 16 f32 each
  const int kb = tid >> 3, nb = (tid & 7) * 16;  // B staging: 8 thr/k-row, 16 f32 each

  f32x4 acc[4][4] = {};

  for (int kt = 0; kt < 1024; kt += 32) {
    {  // stage A = x[brow..+127][kt..+31], split to hi/lo fp16
      const float* src = x + (size_t)(brow + ra) * 1024 + kt + ca;
      u16 hb[16], lb[16];
#pragma unroll
      for (int i = 0; i < 4; ++i) {
        float4 f = ((const float4*)src)[i];
        split_f32(f.x, hb[i * 4 + 0], lb[i * 4 + 0]);
        split_f32(f.y, hb[i * 4 + 1], lb[i * 4 + 1]);
        split_f32(f.z, hb[i * 4 + 2], lb[i * 4 + 2]);
        split_f32(f.w, hb[i * 4 + 3], lb[i * 4 + 3]);
      }
#pragma unroll
      for (int h = 0; h < 2; ++h) {
        u16x8 ph, pl;
#pragma unroll
        for (int j = 0; j < 8; ++j) { ph[j] = hb[h * 8 + j]; pl[j] = lb[h * 8 + j]; }
        *(u16x8*)&sAh[ra][ca + h * 8] = ph;
        *(u16x8*)&sAl[ra][ca + h * 8] = pl;
      }
    }
    {  // stage B = W[kt..+31][bcol..+127], transposed to [n][k]
      const float* src = W + (size_t)(kt + kb) * 1024 + bcol + nb;
#pragma unroll
      for (int i = 0; i < 4; ++i) {
        float4 f = ((const float4*)src)[i];
        u16 hb, lb;
        split_f32(f.x, hb, lb); sBh[nb + i * 4 + 0][kb] = hb; sBl[nb + i * 4 + 0][kb] = lb;
        split_f32(f.y, hb, lb); sBh[nb + i * 4 + 1][kb] = hb; sBl[nb + i * 4 + 1][kb] = lb;
        split_f32(f.z, hb, lb); sBh[nb + i * 4 + 2][kb] = hb; sBl[nb + i * 4 + 2][kb] = lb;
        split_f32(f.w, hb, lb); sBh[nb + i * 4 + 3][kb] = hb; sBl[nb + i * 4 + 3][kb] = lb;
      }
    }
    __syncthreads();
    f16x8 ahm[4], alm[4], bhn[4], bln[4];
#pragma unroll
    for (int m = 0; m < 4; ++m) {
      ahm[m] = *(const f16x8*)&sAh[wr * 64 + m * 16 + ar][k0];
      alm[m] = *(const f16x8*)&sAl[wr * 64 + m * 16 + ar][k0];
      bhn[m] = *(const f16x8*)&sBh[wc * 64 + m * 16 + ar][k0];
      bln[m] = *(const f16x8*)&sBl[wc * 64 + m * 16 + ar][k0];
    }
#pragma unroll
    for (int m = 0; m < 4; ++m)
#pragma unroll
      for (int n = 0; n < 4; ++n) {
        acc[m][n] = __builtin_amdgcn_mfma_f32_16x16x32_f16(ahm[m], bhn[n], acc[m][n], 0, 0, 0);
        acc[m][n] = __builtin_amdgcn_mfma_f32_16x16x32_f16(ahm[m], bln[n], acc[m][n], 0, 0, 0);
        acc[m][n] = __builtin_amdgcn_mfma_f32_16x16x32_f16(alm[m], bhn[n], acc[m][n], 0, 0, 0);
      }
    __syncthreads();
  }

#pragma unroll
  for (int m = 0; m < 4; ++m)
#pragma unroll
    for (int n = 0; n < 4; ++n)
#pragma unroll
      for (int j = 0; j < 4; ++j) {
        const int row = brow + wr * 64 + m * 16 + (lane >> 4) * 4 + j;
        const int col = bcol + wc * 64 + n * 16 + (lane & 15);
        const size_t idx = (size_t)row * 1024 + col;
        const float v = acc[m][n][j];
        if (z == 0) {
          f16 hh = (f16)v; Qh[idx] = hh; Ql[idx] = (f16)(v - (float)hh);
        } else if (z == 1) {
          f16 hh = (f16)v; Kh[idx] = hh; Kl[idx] = (f16)(v - (float)hh);
        } else {
          Vh[idx] = (f16)v;
        }
      }
}

// ---------------- K2: S = (Q @ K^T) / 32  (split fp16, 3-MFMA) ----------------
__global__ __launch_bounds__(256) void k_scores(
    const f16* __restrict__ Qh, const f16* __restrict__ Ql,
    const f16* __restrict__ Kh, const f16* __restrict__ Kl,
    float* __restrict__ S) {
  __shared__ u16 sQh[128][LDP], sQl[128][LDP], sKh[128][LDP], sKl[128][LDP];
  const int tid = threadIdx.x;
  const int lane = tid & 63, wid = tid >> 6;
  const int wr = wid >> 1, wc = wid & 1;
  const int brow = blockIdx.x * 128, bcol = blockIdx.y * 128;
  const int ar = lane & 15, k0 = (lane >> 4) * 8;
  const int ra = tid >> 1, ca = (tid & 1) * 16;

  f32x4 acc[4][4] = {};

  for (int kt = 0; kt < 1024; kt += 32) {
    {
      const size_t qoff = (size_t)(brow + ra) * 1024 + kt + ca;
      const size_t koff = (size_t)(bcol + ra) * 1024 + kt + ca;
      *(u16x8*)&sQh[ra][ca]     = ((const u16x8*)(Qh + qoff))[0];
      *(u16x8*)&sQh[ra][ca + 8] = ((const u16x8*)(Qh + qoff))[1];
      *(u16x8*)&sQl[ra][ca]     = ((const u16x8*)(Ql + qoff))[0];
      *(u16x8*)&sQl[ra][ca + 8] = ((const u16x8*)(Ql + qoff))[1];
      *(u16x8*)&sKh[ra][ca]     = ((const u16x8*)(Kh + koff))[0];
      *(u16x8*)&sKh[ra][ca + 8] = ((const u16x8*)(Kh + koff))[1];
      *(u16x8*)&sKl[ra][ca]     = ((const u16x8*)(Kl + koff))[0];
      *(u16x8*)&sKl[ra][ca + 8] = ((const u16x8*)(Kl + koff))[1];
    }
    __syncthreads();
    f16x8 qh[4], ql[4], kh[4], kl[4];
#pragma unroll
    for (int m = 0; m < 4; ++m) {
      qh[m] = *(const f16x8*)&sQh[wr * 64 + m * 16 + ar][k0];
      ql[m] = *(const f16x8*)&sQl[wr * 64 + m * 16 + ar][k0];
      kh[m] = *(const f16x8*)&sKh[wc * 64 + m * 16 + ar][k0];
      kl[m] = *(const f16x8*)&sKl[wc * 64 + m * 16 + ar][k0];
    }
#pragma unroll
    for (int m = 0; m < 4; ++m)
#pragma unroll
      for (int n = 0; n < 4; ++n) {
        acc[m][n] = __builtin_amdgcn_mfma_f32_16x16x32_f16(qh[m], kh[n], acc[m][n], 0, 0, 0);
        acc[m][n] = __builtin_amdgcn_mfma_f32_16x16x32_f16(qh[m], kl[n], acc[m][n], 0, 0, 0);
        acc[m][n] = __builtin_amdgcn_mfma_f32_16x16x32_f16(ql[m], kh[n], acc[m][n], 0, 0, 0);
      }
    __syncthreads();
  }

#pragma unroll
  for (int m = 0; m < 4; ++m)
#pragma unroll
    for (int n = 0; n < 4; ++n)
#pragma unroll
      for (int j = 0; j < 4; ++j) {
        const int row = brow + wr * 64 + m * 16 + (lane >> 4) * 4 + j;
        const int col = bcol + wc * 64 + n * 16 + (lane & 15);
        S[(size_t)row * 4096 + col] = acc[m][n][j] * 0.03125f;
      }
}

// ---------------- K3: row softmax, S f32 -> P fp16 ----------------
__global__ __launch_bounds__(256) void k_softmax(const float* __restrict__ S,
                                                 f16* __restrict__ P) {
  const int row = blockIdx.x;
  const int tid = threadIdx.x;
  const int lane = tid & 63, wid = tid >> 6;
  const float* s = S + (size_t)row * 4096;
  float4 v[4];
#pragma unroll
  for (int i = 0; i < 4; ++i) v[i] = ((const float4*)s)[tid + 256 * i];

  float mx = -3.4e38f;
#pragma unroll
  for (int i = 0; i < 4; ++i)
    mx = fmaxf(mx, fmaxf(fmaxf(v[i].x, v[i].y), fmaxf(v[i].z, v[i].w)));
#pragma unroll
  for (int off = 1; off < 64; off <<= 1) mx = fmaxf(mx, __shfl_xor(mx, off, 64));
  __shared__ float red[4];
  if (lane == 0) red[wid] = mx;
  __syncthreads();
  mx = fmaxf(fmaxf(red[0], red[1]), fmaxf(red[2], red[3]));

  float sum = 0.f;
#pragma unroll
  for (int i = 0; i < 4; ++i) {
    v[i].x = __expf(v[i].x - mx); v[i].y = __expf(v[i].y - mx);
    v[i].z = __expf(v[i].z - mx); v[i].w = __expf(v[i].w - mx);
    sum += v[i].x + v[i].y + v[i].z + v[i].w;
  }
#pragma unroll
  for (int off = 1; off < 64; off <<= 1) sum += __shfl_xor(sum, off, 64);
  __syncthreads();
  if (lane == 0) red[wid] = sum;
  __syncthreads();
  sum = red[0] + red[1] + red[2] + red[3];
  const float inv = 1.0f / sum;

  f16* p = P + (size_t)row * 4096;
#pragma unroll
  for (int i = 0; i < 4; ++i) {
    f16x4v pv;
    pv[0] = (f16)(v[i].x * inv); pv[1] = (f16)(v[i].y * inv);
    pv[2] = (f16)(v[i].z * inv); pv[3] = (f16)(v[i].w * inv);
    ((f16x4v*)p)[tid + 256 * i] = pv;
  }
}

// ---------------- K4: out = P @ V  (fp16 MFMA) ----------------
__global__ __launch_bounds__(256) void k_pv(const f16* __restrict__ P,
                                            const f16* __restrict__ Vh,
                                            float* __restrict__ out) {
  __shared__ u16 sP[128][LDP], sV[128][LDP];  // sV stored transposed [n][k]
  const int tid = threadIdx.x;
  const int lane = tid & 63, wid = tid >> 6;
  const int wr = wid >> 1, wc = wid & 1;
  const int brow = blockIdx.x * 128, bcol = blockIdx.y * 128;
  const int ar = lane & 15, k0 = (lane >> 4) * 8;
  const int ra = tid >> 1, ca = (tid & 1) * 16;
  const int kb = tid >> 3, nb = (tid & 7) * 16;

  f32x4 acc[4][4] = {};

  for (int kt = 0; kt < 4096; kt += 32) {
    {
      const size_t poff = (size_t)(brow + ra) * 4096 + kt + ca;
      *(u16x8*)&sP[ra][ca]     = ((const u16x8*)(P + poff))[0];
      *(u16x8*)&sP[ra][ca + 8] = ((const u16x8*)(P + poff))[1];
      const f16* vsrc = Vh + (size_t)(kt + kb) * 1024 + bcol + nb;
      u16x8 v0 = ((const u16x8*)vsrc)[0], v1 = ((const u16x8*)vsrc)[1];
#pragma unroll
      for (int i = 0; i < 8; ++i) {
        sV[nb + i][kb] = v0[i];
        sV[nb + 8 + i][kb] = v1[i];
      }
    }
    __syncthreads();
    f16x8 pf[4], vf[4];
#pragma unroll
    for (int m = 0; m < 4; ++m) {
      pf[m] = *(const f16x8*)&sP[wr * 64 + m * 16 + ar][k0];
      vf[m] = *(const f16x8*)&sV[wc * 64 + m * 16 + ar][k0];
    }
#pragma unroll
    for (int m = 0; m < 4; ++m)
#pragma unroll
      for (int n = 0; n < 4; ++n)
        acc[m][n] = __builtin_amdgcn_mfma_f32_16x16x32_f16(pf[m], vf[n], acc[m][n], 0, 0, 0);
    __syncthreads();
  }

#pragma unroll
  for (int m = 0; m < 4; ++m)
#pragma unroll
    for (int n = 0; n < 4; ++n)
#pragma unroll
      for (int j = 0; j < 4; ++j) {
        const int row = brow + wr * 64 + m * 16 + (lane >> 4) * 4 + j;
        const int col = bcol + wc * 64 + n * 16 + (lane & 15);
        out[(size_t)row * 1024 + col] = acc[m][n][j];
      }
}

extern "C" void kernel_launch(void* const* d_in, const int* in_sizes, int n_in,
                              void* d_out, int out_size, void* d_ws, size_t ws_size,
                              hipStream_t stream) {
  const float* x  = (const float*)d_in[0];
  const float* Wq = (const float*)d_in[1];
  const float* Wk = (const float*)d_in[2];
  const float* Wv = (const float*)d_in[3];
  float* out = (float*)d_out;
  char* ws = (char*)d_ws;
  const size_t MiB = 1u << 20;
  f16* Qh = (f16*)(ws + 0 * MiB);
  f16* Ql = (f16*)(ws + 8 * MiB);
  f16* Kh = (f16*)(ws + 16 * MiB);
  f16* Kl = (f16*)(ws + 24 * MiB);
  f16* Vh = (f16*)(ws + 32 * MiB);
  float* S = (float*)(ws + 40 * MiB);  // 64 MiB
  f16* Pm = (f16*)(ws + 0 * MiB);      // 32 MiB, reuses dead Qh/Ql/Kh/Kl

  k_qkv<<<dim3(32, 8, 3), dim3(256), 0, stream>>>(x, Wq, Wk, Wv, Qh, Ql, Kh, Kl, Vh);
  k_scores<<<dim3(32, 32), dim3(256), 0, stream>>>(Qh, Ql, Kh, Kl, S);
  k_softmax<<<dim3(4096), dim3(256), 0, stream>>>(S, Pm);
  k_pv<<<dim3(32, 8), dim3(256), 0, stream>>>(Pm, Vh, out);
}

// Round 2
// 316.569 us; speedup vs baseline: 1.3705x; 1.3705x over previous
//
#include <hip/hip_runtime.h>

// SelfAttention: out = softmax((xWq)(xWk)^T/32) @ (xWv), f32, S=4096, D=1024.
// Numerics: scores ~1e4, near-one-hot softmax, ~200x score->output error
// amplification => Q,K and QK^T use fp16 hi/lo split (3-MFMA). V path only
// needs ~1e-2 => single MFMA.
// Structure: prep kernels split/transposed once; all GEMMs are m97-style
// BT-GEMMs (128x128 tile, BK=64, global_load_lds dwordx4, 4 waves).
// ws layout (MiB), max concurrent 104:
//   Qh 0, Ql 8, Kh 16, Kl 24, Vt 32, S 40..104 (f32)
//   P 0..32 (reuses dead Q/K after K2)
//   temps inside S region (dead before K2): xh 40, xl 48, Wt* 56..68

typedef _Float16 f16;
typedef f16 f16x8 __attribute__((ext_vector_type(8)));
typedef f16 f16x4v __attribute__((ext_vector_type(4)));
typedef float f32x4 __attribute__((ext_vector_type(4)));
typedef unsigned short u16;
typedef u16 u16x8 __attribute__((ext_vector_type(8)));

__device__ __forceinline__ void split_f32(float v, f16& h, f16& l) {
  h = (f16)v;
  l = (f16)(v - (float)h);
}

__device__ __forceinline__ void gload16(const void* g, void* l) {
  __builtin_amdgcn_global_load_lds(
      (const __attribute__((address_space(1))) void*)g,
      (__attribute__((address_space(3))) void*)l, 16, 0, 0);
}

// ---- prep: split x -> xh, xl (f16) ----
__global__ __launch_bounds__(256) void k_xsplit(const float* __restrict__ x,
                                                f16* __restrict__ xh,
                                                f16* __restrict__ xl) {
  const size_t i = ((size_t)blockIdx.x * 256 + threadIdx.x) * 4;
  float4 f = *(const float4*)&x[i];
  f16x4v h, l;
  f16 hh, ll;
  split_f32(f.x, hh, ll); h[0] = hh; l[0] = ll;
  split_f32(f.y, hh, ll); h[1] = hh; l[1] = ll;
  split_f32(f.z, hh, ll); h[2] = hh; l[2] = ll;
  split_f32(f.w, hh, ll); h[3] = hh; l[3] = ll;
  *(f16x4v*)&xh[i] = h;
  *(f16x4v*)&xl[i] = l;
}

// ---- prep: transpose+split W [k][n] f32 -> Wt_h, Wt_l [n][k] f16 ----
__global__ __launch_bounds__(256) void k_wsplit(
    const float* __restrict__ Wq, const float* __restrict__ Wk,
    const float* __restrict__ Wv, f16* __restrict__ qh, f16* __restrict__ ql,
    f16* __restrict__ kh, f16* __restrict__ kl, f16* __restrict__ vh,
    f16* __restrict__ vl) {
  __shared__ float sh[64][65];
  const int z = blockIdx.z;
  const float* __restrict__ W = (z == 0) ? Wq : (z == 1) ? Wk : Wv;
  f16* __restrict__ oh = (z == 0) ? qh : (z == 1) ? kh : vh;
  f16* __restrict__ ol = (z == 0) ? ql : (z == 1) ? kl : vl;
  const int kb = blockIdx.x * 64, nb = blockIdx.y * 64;
  const int t = threadIdx.x;
  const int r = t >> 2, c4 = (t & 3) * 16;
#pragma unroll
  for (int i = 0; i < 4; ++i) {
    float4 f = *(const float4*)&W[(size_t)(kb + r) * 1024 + nb + c4 + i * 4];
    sh[r][c4 + i * 4 + 0] = f.x;
    sh[r][c4 + i * 4 + 1] = f.y;
    sh[r][c4 + i * 4 + 2] = f.z;
    sh[r][c4 + i * 4 + 3] = f.w;
  }
  __syncthreads();
  const int n = t >> 2, ks = (t & 3) * 16;
  u16x8 h0, h1, l0, l1;
#pragma unroll
  for (int i = 0; i < 8; ++i) {
    f16 h, l;
    split_f32(sh[ks + i][n], h, l);
    h0[i] = __builtin_bit_cast(u16, h);
    l0[i] = __builtin_bit_cast(u16, l);
    split_f32(sh[ks + 8 + i][n], h, l);
    h1[i] = __builtin_bit_cast(u16, h);
    l1[i] = __builtin_bit_cast(u16, l);
  }
  const size_t o = (size_t)(nb + n) * 1024 + kb + ks;
  *(u16x8*)&oh[o] = h0;
  *(u16x8*)&oh[o + 8] = h1;
  *(u16x8*)&ol[o] = l0;
  *(u16x8*)&ol[o + 8] = l1;
}

// ---- generic BT-GEMM: C[M][N] = A[M][K] . B[N][K]^T ----
// NM=3: split product Ah.Bh + Ah.Bl + Al.Bh.  NM=1: Ah.Bh only.
// OUT=0: f32 out*scale; OUT=1: split f16 out (oh,ol); OUT=2: f16 out (oh).
template <int NM, int OUT>
__global__ __launch_bounds__(256) void gemm_bt(
    const f16* __restrict__ A, const f16* __restrict__ Al,
    const f16* __restrict__ B, const f16* __restrict__ Bl, int K,
    float* __restrict__ outf, f16* __restrict__ oh, f16* __restrict__ ol,
    int ldo, float scale) {
  extern __shared__ f16 smem[];
  f16* tAh = smem;          // [128][64]
  f16* tBh = smem + 8192;   // [128][64]
  f16* tAl = smem + 16384;  // NM==3 only
  f16* tBl = smem + 24576;

  const int tid = threadIdx.x;
  const int lane = tid & 63, wid = tid >> 6;
  const int wr = wid >> 1, wc = wid & 1;
  const int brow = blockIdx.x * 128, bcol = blockIdx.y * 128;
  const int ar = lane & 15, k0 = (lane >> 4) * 8;
  const int crow = lane >> 3, ccol = (lane & 7) * 8;

  f32x4 acc[4][4] = {};
  const size_t aoff = (size_t)crow * K + ccol;

  for (int kt = 0; kt < K; kt += 64) {
    const f16* Ab = A + (size_t)brow * K + kt;
    const f16* Bb = B + (size_t)bcol * K + kt;
#pragma unroll
    for (int cc = 0; cc < 4; ++cc) {
      const int c = wid * 4 + cc;
      const size_t co = (size_t)c * 8 * K + aoff;
      gload16(Ab + co, tAh + c * 512);
      gload16(Bb + co, tBh + c * 512);
      if constexpr (NM == 3) {
        gload16(Al + (size_t)brow * K + kt + co, tAl + c * 512);
        gload16(Bl + (size_t)bcol * K + kt + co, tBl + c * 512);
      }
    }
    __syncthreads();
#pragma unroll
    for (int ks = 0; ks < 2; ++ks) {
      f16x8 ah[4], bh[4], alv[4], blv[4];
#pragma unroll
      for (int m = 0; m < 4; ++m) {
        ah[m] = *(const f16x8*)&tAh[(wr * 64 + m * 16 + ar) * 64 + ks * 32 + k0];
        bh[m] = *(const f16x8*)&tBh[(wc * 64 + m * 16 + ar) * 64 + ks * 32 + k0];
        if constexpr (NM == 3) {
          alv[m] = *(const f16x8*)&tAl[(wr * 64 + m * 16 + ar) * 64 + ks * 32 + k0];
          blv[m] = *(const f16x8*)&tBl[(wc * 64 + m * 16 + ar) * 64 + ks * 32 + k0];
        }
      }
#pragma unroll
      for (int m = 0; m < 4; ++m)
#pragma unroll
        for (int n = 0; n < 4; ++n) {
          acc[m][n] = __builtin_amdgcn_mfma_f32_16x16x32_f16(ah[m], bh[n], acc[m][n], 0, 0, 0);
          if constexpr (NM == 3) {
            acc[m][n] = __builtin_amdgcn_mfma_f32_16x16x32_f16(ah[m], blv[n], acc[m][n], 0, 0, 0);
            acc[m][n] = __builtin_amdgcn_mfma_f32_16x16x32_f16(alv[m], bh[n], acc[m][n], 0, 0, 0);
          }
        }
    }
    __syncthreads();
  }

#pragma unroll
  for (int m = 0; m < 4; ++m)
#pragma unroll
    for (int n = 0; n < 4; ++n)
#pragma unroll
      for (int j = 0; j < 4; ++j) {
        const int row = brow + wr * 64 + m * 16 + (lane >> 4) * 4 + j;
        const int col = bcol + wc * 64 + n * 16 + ar;
        const size_t idx = (size_t)row * ldo + col;
        const float v = acc[m][n][j] * scale;
        if constexpr (OUT == 0) {
          outf[idx] = v;
        } else if constexpr (OUT == 1) {
          f16 h, l;
          split_f32(v, h, l);
          oh[idx] = h;
          ol[idx] = l;
        } else {
          oh[idx] = (f16)v;
        }
      }
}

// ---- row softmax: S f32 [4096][4096] -> P f16 ----
__global__ __launch_bounds__(256) void k_softmax(const float* __restrict__ S,
                                                 f16* __restrict__ P) {
  const int row = blockIdx.x;
  const int tid = threadIdx.x;
  const int lane = tid & 63, wid = tid >> 6;
  const float* s = S + (size_t)row * 4096;
  float4 v[4];
#pragma unroll
  for (int i = 0; i < 4; ++i) v[i] = ((const float4*)s)[tid + 256 * i];

  float mx = -3.4e38f;
#pragma unroll
  for (int i = 0; i < 4; ++i)
    mx = fmaxf(mx, fmaxf(fmaxf(v[i].x, v[i].y), fmaxf(v[i].z, v[i].w)));
#pragma unroll
  for (int off = 1; off < 64; off <<= 1) mx = fmaxf(mx, __shfl_xor(mx, off, 64));
  __shared__ float red[4];
  if (lane == 0) red[wid] = mx;
  __syncthreads();
  mx = fmaxf(fmaxf(red[0], red[1]), fmaxf(red[2], red[3]));

  float sum = 0.f;
#pragma unroll
  for (int i = 0; i < 4; ++i) {
    v[i].x = __expf(v[i].x - mx); v[i].y = __expf(v[i].y - mx);
    v[i].z = __expf(v[i].z - mx); v[i].w = __expf(v[i].w - mx);
    sum += v[i].x + v[i].y + v[i].z + v[i].w;
  }
#pragma unroll
  for (int off = 1; off < 64; off <<= 1) sum += __shfl_xor(sum, off, 64);
  __syncthreads();
  if (lane == 0) red[wid] = sum;
  __syncthreads();
  sum = red[0] + red[1] + red[2] + red[3];
  const float inv = 1.0f / sum;

  f16* p = P + (size_t)row * 4096;
#pragma unroll
  for (int i = 0; i < 4; ++i) {
    f16x4v pv;
    pv[0] = (f16)(v[i].x * inv); pv[1] = (f16)(v[i].y * inv);
    pv[2] = (f16)(v[i].z * inv); pv[3] = (f16)(v[i].w * inv);
    ((f16x4v*)p)[tid + 256 * i] = pv;
  }
}

extern "C" void kernel_launch(void* const* d_in, const int* in_sizes, int n_in,
                              void* d_out, int out_size, void* d_ws,
                              size_t ws_size, hipStream_t stream) {
  const float* x = (const float*)d_in[0];
  const float* Wq = (const float*)d_in[1];
  const float* Wk = (const float*)d_in[2];
  const float* Wv = (const float*)d_in[3];
  float* out = (float*)d_out;
  char* ws = (char*)d_ws;
  const size_t MiB = 1u << 20;
  f16* Qh = (f16*)(ws + 0 * MiB);
  f16* Ql = (f16*)(ws + 8 * MiB);
  f16* Kh = (f16*)(ws + 16 * MiB);
  f16* Kl = (f16*)(ws + 24 * MiB);
  f16* Vt = (f16*)(ws + 32 * MiB);
  float* S = (float*)(ws + 40 * MiB);  // 64 MiB
  f16* Pm = (f16*)(ws + 0 * MiB);      // reuses dead Q/K
  // temps living inside the (not-yet-written) S region:
  f16* xh = (f16*)(ws + 40 * MiB);
  f16* xl = (f16*)(ws + 48 * MiB);
  f16* Wtqh = (f16*)(ws + 56 * MiB);
  f16* Wtql = (f16*)(ws + 58 * MiB);
  f16* Wtkh = (f16*)(ws + 60 * MiB);
  f16* Wtkl = (f16*)(ws + 62 * MiB);
  f16* Wtvh = (f16*)(ws + 64 * MiB);
  f16* Wtvl = (f16*)(ws + 66 * MiB);

  k_wsplit<<<dim3(16, 16, 3), 256, 0, stream>>>(Wq, Wk, Wv, Wtqh, Wtql, Wtkh,
                                                Wtkl, Wtvh, Wtvl);
  k_xsplit<<<dim3(4096), 256, 0, stream>>>(x, xh, xl);
  // Q = x@Wq (split out), K = x@Wk (split out)
  gemm_bt<3, 1><<<dim3(32, 8), 256, 65536, stream>>>(
      xh, xl, Wtqh, Wtql, 1024, nullptr, Qh, Ql, 1024, 1.0f);
  gemm_bt<3, 1><<<dim3(32, 8), 256, 65536, stream>>>(
      xh, xl, Wtkh, Wtkl, 1024, nullptr, Kh, Kl, 1024, 1.0f);
  // Vt[dv][seq] = (x@Wv)^T = Wvt . xh^T  (single MFMA precision)
  gemm_bt<1, 2><<<dim3(8, 32), 256, 32768, stream>>>(
      Wtvh, nullptr, xh, nullptr, 1024, nullptr, Vt, nullptr, 4096, 1.0f);
  // S = (Q.K^T)/32
  gemm_bt<3, 0><<<dim3(32, 32), 256, 65536, stream>>>(
      Qh, Ql, Kh, Kl, 1024, S, nullptr, nullptr, 4096, 0.03125f);
  k_softmax<<<dim3(4096), 256, 0, stream>>>(S, Pm);
  // out = P @ V = P . Vt^T
  gemm_bt<1, 0><<<dim3(32, 8), 256, 32768, stream>>>(
      Pm, nullptr, Vt, nullptr, 4096, out, nullptr, nullptr, 1024, 1.0f);
}